// Round 1
// baseline (267.565 us; speedup 1.0000x reference)
//
#include <hip/hip_runtime.h>
#include <cstdint>
#include <cstddef>

typedef unsigned short u16;
typedef unsigned int   u32;

typedef __bf16 bf8   __attribute__((ext_vector_type(8)));
typedef float  f32x4 __attribute__((ext_vector_type(4)));

__device__ __forceinline__ float b2f(u16 v) {
  union { u32 i; float f; } c; c.i = ((u32)v) << 16; return c.f;
}
__device__ __forceinline__ u16 f2b(float f) {
  union { u32 i; float f; } c; c.f = f;
  u32 x = c.i;
  u32 r = (x + 0x7FFFu + ((x >> 16) & 1u)) >> 16;
  return (u16)r;
}
__device__ __forceinline__ float sigf(float x) { return 1.0f / (1.0f + __expf(-x)); }
__device__ __forceinline__ float tanhfast(float x) { return 2.0f * sigf(2.0f * x) - 1.0f; }

// convert 8 consecutive floats to a bf16x8 fragment (RNE)
__device__ __forceinline__ bf8 cvt8(const float* __restrict__ p) {
  f32x4 lo = *(const f32x4*)p;
  f32x4 hi = *(const f32x4*)(p + 4);
  union { u16 s[8]; bf8 v; } c;
#pragma unroll
  for (int i = 0; i < 4; ++i) { c.s[i] = f2b(lo[i]); c.s[4 + i] = f2b(hi[i]); }
  return c.v;
}
__device__ __forceinline__ bf8 asbf8(uint4 q) {
  union { uint4 q; bf8 v; } c; c.q = q; return c.v;
}

// async 16B global -> LDS (dest = wave-uniform base + lane*16)
__device__ __forceinline__ void ld_lds16(const u16* g, u16* l) {
  __builtin_amdgcn_global_load_lds((const __attribute__((address_space(1))) void*)g,
                                   (__attribute__((address_space(3))) void*)l, 16, 0, 0);
}

#define CSR_STRIDE 80

// ---- weight repack: W fp32 [K x 128] -> Bt bf16 in MFMA-fragment order ----
// frag id f = (hh*4+ks)*512 + c*64 + lane ; element j in [0,8):
//   Bt[f*8+j] = bf16( W[(hh*128+ks*32+quad*8+j)*128 + (c*16+ln)] )   (lane=quad*16+ln)
// blocks >= 64 zero the degree-count array instead.
__global__ __launch_bounds__(256) void k_transpose(
    const float* __restrict__ W0, const float* __restrict__ W1,
    const float* __restrict__ W2, const float* __restrict__ W3,
    const float* __restrict__ W4,
    u16* __restrict__ B0, u16* __restrict__ B1, u16* __restrict__ B2,
    u16* __restrict__ B3, u16* __restrict__ B4,
    int* __restrict__ cnt, int N) {
  if (blockIdx.x >= 64) {
    int i = (blockIdx.x - 64) * 256 + threadIdx.x;
    if (i < N) cnt[i] = 0;
    return;
  }
  int t = blockIdx.x * 256 + threadIdx.x;
  const float* in; u16* out; int f;
  if (t < 2048)       { in = W0; out = B0; f = t; }
  else if (t < 4096)  { in = W1; out = B1; f = t - 2048; }
  else if (t < 8192)  { in = W2; out = B2; f = t - 4096; }
  else if (t < 12288) { in = W3; out = B3; f = t - 8192; }
  else                { in = W4; out = B4; f = t - 12288; }
  int ln = f & 15, quad = (f >> 4) & 3, c = (f >> 6) & 7, ks = (f >> 9) & 3, hh = f >> 11;
  int n = c * 16 + ln;
  int k0 = hh * 128 + ks * 32 + quad * 8;
  union { u16 s[8]; uint4 q; } tmp;
#pragma unroll
  for (int j = 0; j < 8; ++j) tmp.s[j] = f2b(in[(size_t)(k0 + j) * 128 + n]);
  *(uint4*)(out + (size_t)f * 8) = tmp.q;
}

// ---------------- CSR build: one pass; cnt doubles as cursor and final degree ----------------
__global__ void k_fill(const int* __restrict__ src, const int* __restrict__ dst,
                       int* __restrict__ cnt, int* __restrict__ csr, int E) {
  int e = blockIdx.x * 256 + threadIdx.x;
  if (e < E) {
    int d = dst[e];
    int pos = atomicAdd(&cnt[d], 1);
    if (pos < CSR_STRIDE) csr[(size_t)d * CSR_STRIDE + pos] = src[e];
  }
}

// ---------------- aggregation: one wave per node, 4 edges x 16-lane x 16B ----------------
// out[d] = postproc( rsqrt(deg+1) * (sum_{s->d} y[s] + y[d]) + bias )
__global__ __launch_bounds__(256) void k_agg(const u16* __restrict__ y,
                                             const int* __restrict__ cnt,
                                             const int* __restrict__ csr,
                                             const float* __restrict__ bias,
                                             u16* __restrict__ out, int relu, int N) {
  int wv = (blockIdx.x * 256 + threadIdx.x) >> 6;
  int lane = threadIdx.x & 63;
  if (wv >= N) return;
  int g = lane >> 4, t = lane & 15;
  const uint4* yq = (const uint4*)y;        // 16 uint4 per 128-feat bf16 row
  int deg = cnt[wv];
  int degc = (deg < 64) ? deg : 64;
  long base = (long)wv * CSR_STRIDE;
  int myidx = (lane < degc) ? csr[base + lane] : 0;

  float a[8];
#pragma unroll
  for (int j = 0; j < 8; ++j) a[j] = 0.0f;

  for (int b = 0; b < degc; b += 8) {
    int e0 = b + g, e1 = b + 4 + g;
    int s0 = __shfl(myidx, (e0 < degc) ? e0 : 0, 64);
    int s1 = __shfl(myidx, (e1 < degc) ? e1 : 0, 64);
    uint4 v0 = yq[(size_t)s0 * 16 + t];
    uint4 v1 = yq[(size_t)s1 * 16 + t];
    if (e0 < degc) {
      const u32* w = (const u32*)&v0;
#pragma unroll
      for (int i = 0; i < 4; ++i) { a[2*i] += b2f((u16)(w[i] & 0xFFFF)); a[2*i+1] += b2f((u16)(w[i] >> 16)); }
    }
    if (e1 < degc) {
      const u32* w = (const u32*)&v1;
#pragma unroll
      for (int i = 0; i < 4; ++i) { a[2*i] += b2f((u16)(w[i] & 0xFFFF)); a[2*i+1] += b2f((u16)(w[i] >> 16)); }
    }
  }
  // cross-group reduction: groups 0..3 hold partial sums of the same feature slice
#pragma unroll
  for (int j = 0; j < 8; ++j) {
    a[j] += __shfl_xor(a[j], 16, 64);
    a[j] += __shfl_xor(a[j], 32, 64);
  }
  if (g == 0) {
    // rare tail deg in (64, 80): add serially (16 lanes do full rows)
    int degt = (deg < CSR_STRIDE) ? deg : CSR_STRIDE;
    for (int p = 64; p < degt; ++p) {
      int s = csr[base + p];
      uint4 v = yq[(size_t)s * 16 + t];
      const u32* w = (const u32*)&v;
#pragma unroll
      for (int i = 0; i < 4; ++i) { a[2*i] += b2f((u16)(w[i] & 0xFFFF)); a[2*i+1] += b2f((u16)(w[i] >> 16)); }
    }
    // self-loop
    uint4 sv = yq[(size_t)wv * 16 + t];
    const u32* w = (const u32*)&sv;
#pragma unroll
    for (int i = 0; i < 4; ++i) { a[2*i] += b2f((u16)(w[i] & 0xFFFF)); a[2*i+1] += b2f((u16)(w[i] >> 16)); }
    float di = rsqrtf((float)deg + 1.0f);
    f32x4 b0 = *(const f32x4*)(bias + t * 8);
    f32x4 b1 = *(const f32x4*)(bias + t * 8 + 4);
    union { u16 s[8]; uint4 q; } o;
#pragma unroll
    for (int j = 0; j < 8; ++j) {
      float r = di * a[j] + ((j < 4) ? b0[j] : b1[j - 4]);
      if (relu) r = fmaxf(r, 0.0f);
      o.s[j] = f2b(r);
    }
    ((uint4*)out)[(size_t)wv * 16 + t] = o.q;
  }
}

// ---------------- layer GEMM: y[M,128] = bf16( (A[M,128] @ W) * rsqrt(deg+1)[row] ) ----------------
template <bool AF>   // A is fp32 (convert) or bf16
__global__ __launch_bounds__(256) void k_gemm(
    const void* __restrict__ Av,
    const u16* __restrict__ Bt,          // fragment-ordered, 16384 u16
    const int* __restrict__ cnt,
    u16* __restrict__ outb, int M) {
  __shared__ __align__(16) u16 bs[16384];
  int tid = threadIdx.x;
  int lane = tid & 63, wave = tid >> 6;
  int ln = lane & 15, quad = lane >> 4;
  int rowbase = blockIdx.x * 64 + wave * 16;
  int rowA = rowbase + ln;
  long rA = (rowA < M) ? rowA : (M - 1);

  {
    const u16* g = Bt + wave * 4096 + lane * 8;
    u16* l = bs + wave * 4096;
#pragma unroll
    for (int i = 0; i < 8; ++i) ld_lds16(g + i * 512, l + i * 512);
  }

  bf8 af[4];
#pragma unroll
  for (int ks = 0; ks < 4; ++ks) {
    int kk = ks * 32 + quad * 8;
    if (AF) af[ks] = cvt8((const float*)Av + rA * 128 + kk);
    else    af[ks] = *(const bf8*)((const u16*)Av + rA * 128 + kk);
  }

  f32x4 acc[8];
#pragma unroll
  for (int c = 0; c < 8; ++c) { acc[c][0] = 0.f; acc[c][1] = 0.f; acc[c][2] = 0.f; acc[c][3] = 0.f; }

  __syncthreads();   // drains the async LDS DMA
#pragma unroll
  for (int ks = 0; ks < 4; ++ks) {
#pragma unroll
    for (int c = 0; c < 8; ++c) {
      bf8 bfr = *(const bf8*)(bs + ks * 4096 + c * 512 + lane * 8);
      acc[c] = __builtin_amdgcn_mfma_f32_16x16x32_bf16(af[ks], bfr, acc[c], 0, 0, 0);
    }
  }

  int rb = rowbase + quad * 4;
  float rs[4];
#pragma unroll
  for (int r = 0; r < 4; ++r) {
    int row = rb + r;
    rs[r] = (row < M) ? rsqrtf((float)cnt[row] + 1.0f) : 0.0f;
  }
#pragma unroll
  for (int c = 0; c < 8; ++c) {
    int col = c * 16 + ln;
#pragma unroll
    for (int r = 0; r < 4; ++r) {
      int row = rb + r;
      if (row < M) outb[(size_t)row * 128 + col] = f2b(acc[c][r] * rs[r]);
    }
  }
}

// ---------------- fused GRU, global-streamed weights, 1 barrier ----------------
// out = (1-u)*h + u*tanh([emb | sig(r)*h] @ Wc + bc); u = sig([emb|h]@Wz+bz)
__global__ __launch_bounds__(256, 2) void k_gru(
    const u16* __restrict__ emb, const float* __restrict__ h,
    const u16* __restrict__ Btz, const u16* __restrict__ Btr, const u16* __restrict__ Btc,
    const float* __restrict__ bz, const float* __restrict__ br, const float* __restrict__ bc,
    float* __restrict__ out, int M) {
  __shared__ __align__(16) u16 at[8192];    // 16 KB rh A-tile, stride 128
  int tid = threadIdx.x;
  int lane = tid & 63, wave = tid >> 6;
  int ln = lane & 15, quad = lane >> 4;
  int rowbase = blockIdx.x * 64 + wave * 16;
  int rowA = rowbase + ln;
  long rA = (rowA < M) ? rowA : (M - 1);
  int rb = rowbase + quad * 4;

  const uint4* Bz = (const uint4*)Btz;
  const uint4* Br = (const uint4*)Btr;
  const uint4* Bc = (const uint4*)Btc;

  // A fragments (registers, reused across all three GEMMs)
  bf8 af_e[4], af_h[4];
#pragma unroll
  for (int ks = 0; ks < 4; ++ks)
    af_e[ks] = *(const bf8*)(emb + rA * 128 + ks * 32 + quad * 8);
#pragma unroll
  for (int ks = 0; ks < 4; ++ks)
    af_h[ks] = cvt8(h + rA * 128 + ks * 32 + quad * 8);

  f32x4 accz[8], accr[8];
#pragma unroll
  for (int c = 0; c < 8; ++c) {
    accz[c][0] = 0.f; accz[c][1] = 0.f; accz[c][2] = 0.f; accz[c][3] = 0.f;
    accr[c][0] = 0.f; accr[c][1] = 0.f; accr[c][2] = 0.f; accr[c][3] = 0.f;
  }

  auto loadb = [&](uint4 (&d)[8], const uint4* B, int ksg) {
#pragma unroll
    for (int c = 0; c < 8; ++c) d[c] = B[(size_t)ksg * 512 + c * 64 + lane];
  };
  auto mmzr = [&](uint4 (&cz)[8], uint4 (&cr)[8], int ksg) {
    bf8 af = (ksg < 4) ? af_e[ksg] : af_h[ksg - 4];
#pragma unroll
    for (int c = 0; c < 8; ++c) {
      accz[c] = __builtin_amdgcn_mfma_f32_16x16x32_bf16(af, asbf8(cz[c]), accz[c], 0, 0, 0);
      accr[c] = __builtin_amdgcn_mfma_f32_16x16x32_bf16(af, asbf8(cr[c]), accr[c], 0, 0, 0);
    }
  };

  // z/r pass: ping-pong prefetch, MFMA interleaved with in-flight loads
  uint4 z0[8], r0[8], z1[8], r1[8];
  loadb(z0, Bz, 0); loadb(r0, Br, 0);
  loadb(z1, Bz, 1); loadb(r1, Br, 1);
  mmzr(z0, r0, 0);
  loadb(z0, Bz, 2); loadb(r0, Br, 2);
  mmzr(z1, r1, 1);
  loadb(z1, Bz, 3); loadb(r1, Br, 3);
  mmzr(z0, r0, 2);
  loadb(z0, Bz, 4); loadb(r0, Br, 4);
  mmzr(z1, r1, 3);
  loadb(z1, Bz, 5); loadb(r1, Br, 5);
  mmzr(z0, r0, 4);
  loadb(z0, Bz, 6); loadb(r0, Br, 6);
  mmzr(z1, r1, 5);
  loadb(z1, Bz, 7); loadb(r1, Br, 7);
  mmzr(z0, r0, 6);
  mmzr(z1, r1, 7);

  // h at C-layout positions (for rh and final blend)
  f32x4 hc[8];
#pragma unroll
  for (int c = 0; c < 8; ++c) {
    int col = c * 16 + ln;
#pragma unroll
    for (int r = 0; r < 4; ++r) {
      int row = rb + r;
      hc[c][r] = (row < M) ? h[(size_t)row * 128 + col] : 0.0f;
    }
  }

  // u = sigmoid(accz+bz); rh = sigmoid(accr+br)*h -> at (A-source tile)
#pragma unroll
  for (int c = 0; c < 8; ++c) {
    int col = c * 16 + ln;
    float bzc = bz[col], brc = br[col];
#pragma unroll
    for (int r = 0; r < 4; ++r) {
      float uu = sigf(accz[c][r] + bzc);
      float rr = sigf(accr[c][r] + brc);
      accz[c][r] = uu;                       // keep u in registers
      int lrow = wave * 16 + quad * 4 + r;   // local block row
      at[lrow * 128 + col] = f2b(rr * hc[c][r]);
      accr[c][r] = 0.0f;                     // accr becomes candidate accumulator
    }
  }
  __syncthreads();                           // the ONLY barrier: at visible

  bf8 af_at[4];
#pragma unroll
  for (int ks = 0; ks < 4; ++ks)
    af_at[ks] = *(const bf8*)(at + (wave * 16 + ln) * 128 + ks * 32 + quad * 8);

  auto mmc = [&](uint4 (&cc)[8], int ksg) {
    bf8 af = (ksg < 4) ? af_e[ksg] : af_at[ksg - 4];
#pragma unroll
    for (int c = 0; c < 8; ++c)
      accr[c] = __builtin_amdgcn_mfma_f32_16x16x32_bf16(af, asbf8(cc[c]), accr[c], 0, 0, 0);
  };
  uint4 c0[8], c1[8];
  loadb(c0, Bc, 0);
  loadb(c1, Bc, 1);
  mmc(c0, 0);
  loadb(c0, Bc, 2);
  mmc(c1, 1);
  loadb(c1, Bc, 3);
  mmc(c0, 2);
  loadb(c0, Bc, 4);
  mmc(c1, 3);
  loadb(c1, Bc, 5);
  mmc(c0, 4);
  loadb(c0, Bc, 6);
  mmc(c1, 5);
  loadb(c1, Bc, 7);
  mmc(c0, 6);
  mmc(c1, 7);

  // epilogue: out = (1-u)*h + u*tanh(accc + bc)
#pragma unroll
  for (int c = 0; c < 8; ++c) {
    int col = c * 16 + ln;
    float bcc = bc[col];
#pragma unroll
    for (int r = 0; r < 4; ++r) {
      int row = rb + r;
      if (row < M) {
        float cd = tanhfast(accr[c][r] + bcc);
        float uu = accz[c][r];
        out[(size_t)row * 128 + col] = (1.0f - uu) * hc[c][r] + uu * cd;
      }
    }
  }
}

extern "C" void kernel_launch(void* const* d_in, const int* in_sizes, int n_in,
                              void* d_out, int out_size, void* d_ws, size_t ws_size,
                              hipStream_t stream) {
  const float* x     = (const float*)d_in[0];
  const float* h     = (const float*)d_in[1];
  const int*   ei    = (const int*)d_in[2];
  const float* W_in  = (const float*)d_in[3];
  const float* b_in  = (const float*)d_in[4];
  const float* W_hid = (const float*)d_in[5];
  const float* b_hid = (const float*)d_in[6];
  const float* W_z   = (const float*)d_in[7];
  const float* b_z   = (const float*)d_in[8];
  const float* W_r   = (const float*)d_in[9];
  const float* b_r   = (const float*)d_in[10];
  const float* W_c   = (const float*)d_in[11];
  const float* b_c   = (const float*)d_in[12];

  const int N = in_sizes[0] / 128;
  const int E = in_sizes[2] / 2;
  const int* src = ei;
  const int* dst = ei + E;

  char* p = (char*)d_ws;
  auto carve = [&](size_t bytes) { char* r = p; p += (bytes + 255) & ~(size_t)255; return r; };
  u16* Bt_in   = (u16*)carve((size_t)16384 * 2);
  u16* Bt_hid  = (u16*)carve((size_t)16384 * 2);
  u16* Bt_z    = (u16*)carve((size_t)32768 * 2);
  u16* Bt_r    = (u16*)carve((size_t)32768 * 2);
  u16* Bt_c    = (u16*)carve((size_t)32768 * 2);
  int* cnt  = (int*)carve((size_t)N * 4);
  int* csr  = (int*)carve((size_t)N * CSR_STRIDE * 4);
  u16* y    = (u16*)carve((size_t)N * 128 * 2);    // bf16 intermediates
  u16* h1   = (u16*)carve((size_t)N * 128 * 2);
  u16* emb  = (u16*)carve((size_t)N * 128 * 2);

  int gN = (N + 255) / 256;
  int gE = (E + 255) / 256;
  int gG = (N + 63) / 64;      // GEMM/GRU: 64 rows per block
  int gA = (N + 3) / 4;        // AGG: 4 waves (nodes) per block

  k_transpose<<<64 + gN, 256, 0, stream>>>(W_in, W_hid, W_z, W_r, W_c,
                                           Bt_in, Bt_hid, Bt_z, Bt_r, Bt_c, cnt, N);
  k_fill<<<gE, 256, 0, stream>>>(src, dst, cnt, csr, E);

  // layer 1: y = (x @ W_in) * dinv ; h1 = relu(dinv * agg(y) + b_in)
  k_gemm<true><<<gG, 256, 0, stream>>>(x, Bt_in, cnt, y, N);
  k_agg<<<gA, 256, 0, stream>>>(y, cnt, csr, b_in, h1, 1, N);
  // layer 2: y = (h1 @ W_hid) * dinv ; emb = dinv * agg(y) + b_hid
  k_gemm<false><<<gG, 256, 0, stream>>>(h1, Bt_hid, cnt, y, N);
  k_agg<<<gA, 256, 0, stream>>>(y, cnt, csr, b_hid, emb, 0, N);
  // fused GRU
  k_gru<<<gG, 256, 0, stream>>>(emb, h, Bt_z, Bt_r, Bt_c, b_z, b_r, b_c, (float*)d_out, N);
}

// Round 2
// 262.863 us; speedup vs baseline: 1.0179x; 1.0179x over previous
//
#include <hip/hip_runtime.h>
#include <cstdint>
#include <cstddef>

typedef unsigned short u16;
typedef unsigned int   u32;

typedef __bf16 bf8   __attribute__((ext_vector_type(8)));
typedef float  f32x4 __attribute__((ext_vector_type(4)));

__device__ __forceinline__ float b2f(u16 v) {
  union { u32 i; float f; } c; c.i = ((u32)v) << 16; return c.f;
}
__device__ __forceinline__ u16 f2b(float f) {
  union { u32 i; float f; } c; c.f = f;
  u32 x = c.i;
  u32 r = (x + 0x7FFFu + ((x >> 16) & 1u)) >> 16;
  return (u16)r;
}
__device__ __forceinline__ float sigf(float x) { return 1.0f / (1.0f + __expf(-x)); }
__device__ __forceinline__ float tanhfast(float x) { return 2.0f * sigf(2.0f * x) - 1.0f; }

// convert 8 consecutive floats to a bf16x8 fragment (RNE)
__device__ __forceinline__ bf8 cvt8(const float* __restrict__ p) {
  f32x4 lo = *(const f32x4*)p;
  f32x4 hi = *(const f32x4*)(p + 4);
  union { u16 s[8]; bf8 v; } c;
#pragma unroll
  for (int i = 0; i < 4; ++i) { c.s[i] = f2b(lo[i]); c.s[4 + i] = f2b(hi[i]); }
  return c.v;
}

// async 16B global -> LDS (dest = wave-uniform base + lane*16)
__device__ __forceinline__ void ld_lds16(const u16* g, u16* l) {
  __builtin_amdgcn_global_load_lds((const __attribute__((address_space(1))) void*)g,
                                   (__attribute__((address_space(3))) void*)l, 16, 0, 0);
}

#define CSR_STRIDE 80

// ---- weight repack: W fp32 [K x 128] -> Bt bf16 in MFMA-fragment order ----
// frag id f = (hh*4+ks)*512 + c*64 + lane ; element j in [0,8):
//   Bt[f*8+j] = bf16( W[(hh*128+ks*32+quad*8+j)*128 + (c*16+ln)] )   (lane=quad*16+ln)
// blocks >= 64 zero the degree-count array instead.
__global__ __launch_bounds__(256) void k_transpose(
    const float* __restrict__ W0, const float* __restrict__ W1,
    const float* __restrict__ W2, const float* __restrict__ W3,
    const float* __restrict__ W4,
    u16* __restrict__ B0, u16* __restrict__ B1, u16* __restrict__ B2,
    u16* __restrict__ B3, u16* __restrict__ B4,
    int* __restrict__ cnt, int N) {
  if (blockIdx.x >= 64) {
    int i = (blockIdx.x - 64) * 256 + threadIdx.x;
    if (i < N) cnt[i] = 0;
    return;
  }
  int t = blockIdx.x * 256 + threadIdx.x;
  const float* in; u16* out; int f;
  if (t < 2048)       { in = W0; out = B0; f = t; }
  else if (t < 4096)  { in = W1; out = B1; f = t - 2048; }
  else if (t < 8192)  { in = W2; out = B2; f = t - 4096; }
  else if (t < 12288) { in = W3; out = B3; f = t - 8192; }
  else                { in = W4; out = B4; f = t - 12288; }
  int ln = f & 15, quad = (f >> 4) & 3, c = (f >> 6) & 7, ks = (f >> 9) & 3, hh = f >> 11;
  int n = c * 16 + ln;
  int k0 = hh * 128 + ks * 32 + quad * 8;
  union { u16 s[8]; uint4 q; } tmp;
#pragma unroll
  for (int j = 0; j < 8; ++j) tmp.s[j] = f2b(in[(size_t)(k0 + j) * 128 + n]);
  *(uint4*)(out + (size_t)f * 8) = tmp.q;
}

// ---------------- CSR build: one pass; cnt doubles as cursor and final degree ----------------
__global__ void k_fill(const int* __restrict__ src, const int* __restrict__ dst,
                       int* __restrict__ cnt, int* __restrict__ csr, int E) {
  int e = blockIdx.x * 256 + threadIdx.x;
  if (e < E) {
    int d = dst[e];
    int pos = atomicAdd(&cnt[d], 1);
    if (pos < CSR_STRIDE) csr[(size_t)d * CSR_STRIDE + pos] = src[e];
  }
}

// ---------------- aggregation: one wave per node, 4 edges x 16-lane x 16B ----------------
// out[d] = postproc( rsqrt(deg+1) * (sum_{s->d} y[s] + y[d]) + bias )
__global__ __launch_bounds__(256) void k_agg(const u16* __restrict__ y,
                                             const int* __restrict__ cnt,
                                             const int* __restrict__ csr,
                                             const float* __restrict__ bias,
                                             u16* __restrict__ out, int relu, int N) {
  int wv = (blockIdx.x * 256 + threadIdx.x) >> 6;
  int lane = threadIdx.x & 63;
  if (wv >= N) return;
  int g = lane >> 4, t = lane & 15;
  const uint4* yq = (const uint4*)y;        // 16 uint4 per 128-feat bf16 row
  int deg = cnt[wv];
  int degc = (deg < 64) ? deg : 64;
  long base = (long)wv * CSR_STRIDE;
  int myidx = (lane < degc) ? csr[base + lane] : 0;

  float a[8];
#pragma unroll
  for (int j = 0; j < 8; ++j) a[j] = 0.0f;

  for (int b = 0; b < degc; b += 8) {
    int e0 = b + g, e1 = b + 4 + g;
    int s0 = __shfl(myidx, (e0 < degc) ? e0 : 0, 64);
    int s1 = __shfl(myidx, (e1 < degc) ? e1 : 0, 64);
    uint4 v0 = yq[(size_t)s0 * 16 + t];
    uint4 v1 = yq[(size_t)s1 * 16 + t];
    if (e0 < degc) {
      const u32* w = (const u32*)&v0;
#pragma unroll
      for (int i = 0; i < 4; ++i) { a[2*i] += b2f((u16)(w[i] & 0xFFFF)); a[2*i+1] += b2f((u16)(w[i] >> 16)); }
    }
    if (e1 < degc) {
      const u32* w = (const u32*)&v1;
#pragma unroll
      for (int i = 0; i < 4; ++i) { a[2*i] += b2f((u16)(w[i] & 0xFFFF)); a[2*i+1] += b2f((u16)(w[i] >> 16)); }
    }
  }
  // cross-group reduction: groups 0..3 hold partial sums of the same feature slice
#pragma unroll
  for (int j = 0; j < 8; ++j) {
    a[j] += __shfl_xor(a[j], 16, 64);
    a[j] += __shfl_xor(a[j], 32, 64);
  }
  if (g == 0) {
    // rare tail deg in (64, 80): add serially (16 lanes do full rows)
    int degt = (deg < CSR_STRIDE) ? deg : CSR_STRIDE;
    for (int p = 64; p < degt; ++p) {
      int s = csr[base + p];
      uint4 v = yq[(size_t)s * 16 + t];
      const u32* w = (const u32*)&v;
#pragma unroll
      for (int i = 0; i < 4; ++i) { a[2*i] += b2f((u16)(w[i] & 0xFFFF)); a[2*i+1] += b2f((u16)(w[i] >> 16)); }
    }
    // self-loop
    uint4 sv = yq[(size_t)wv * 16 + t];
    const u32* w = (const u32*)&sv;
#pragma unroll
    for (int i = 0; i < 4; ++i) { a[2*i] += b2f((u16)(w[i] & 0xFFFF)); a[2*i+1] += b2f((u16)(w[i] >> 16)); }
    float di = rsqrtf((float)deg + 1.0f);
    f32x4 b0 = *(const f32x4*)(bias + t * 8);
    f32x4 b1 = *(const f32x4*)(bias + t * 8 + 4);
    union { u16 s[8]; uint4 q; } o;
#pragma unroll
    for (int j = 0; j < 8; ++j) {
      float r = di * a[j] + ((j < 4) ? b0[j] : b1[j - 4]);
      if (relu) r = fmaxf(r, 0.0f);
      o.s[j] = f2b(r);
    }
    ((uint4*)out)[(size_t)wv * 16 + t] = o.q;
  }
}

// ---------------- layer GEMM: y[M,128] = bf16( (A[M,128] @ W) * rsqrt(deg+1)[row] ) ----------------
template <bool AF>   // A is fp32 (convert) or bf16
__global__ __launch_bounds__(256) void k_gemm(
    const void* __restrict__ Av,
    const u16* __restrict__ Bt,          // fragment-ordered, 16384 u16
    const int* __restrict__ cnt,
    u16* __restrict__ outb, int M) {
  __shared__ __align__(16) u16 bs[16384];
  int tid = threadIdx.x;
  int lane = tid & 63, wave = tid >> 6;
  int ln = lane & 15, quad = lane >> 4;
  int rowbase = blockIdx.x * 64 + wave * 16;
  int rowA = rowbase + ln;
  long rA = (rowA < M) ? rowA : (M - 1);

  {
    const u16* g = Bt + wave * 4096 + lane * 8;
    u16* l = bs + wave * 4096;
#pragma unroll
    for (int i = 0; i < 8; ++i) ld_lds16(g + i * 512, l + i * 512);
  }

  bf8 af[4];
#pragma unroll
  for (int ks = 0; ks < 4; ++ks) {
    int kk = ks * 32 + quad * 8;
    if (AF) af[ks] = cvt8((const float*)Av + rA * 128 + kk);
    else    af[ks] = *(const bf8*)((const u16*)Av + rA * 128 + kk);
  }

  f32x4 acc[8];
#pragma unroll
  for (int c = 0; c < 8; ++c) { acc[c][0] = 0.f; acc[c][1] = 0.f; acc[c][2] = 0.f; acc[c][3] = 0.f; }

  __syncthreads();   // drains the async LDS DMA
#pragma unroll
  for (int ks = 0; ks < 4; ++ks) {
#pragma unroll
    for (int c = 0; c < 8; ++c) {
      bf8 bfr = *(const bf8*)(bs + ks * 4096 + c * 512 + lane * 8);
      acc[c] = __builtin_amdgcn_mfma_f32_16x16x32_bf16(af[ks], bfr, acc[c], 0, 0, 0);
    }
  }

  int rb = rowbase + quad * 4;
  float rs[4];
#pragma unroll
  for (int r = 0; r < 4; ++r) {
    int row = rb + r;
    rs[r] = (row < M) ? rsqrtf((float)cnt[row] + 1.0f) : 0.0f;
  }
#pragma unroll
  for (int c = 0; c < 8; ++c) {
    int col = c * 16 + ln;
#pragma unroll
    for (int r = 0; r < 4; ++r) {
      int row = rb + r;
      if (row < M) outb[(size_t)row * 128 + col] = f2b(acc[c][r] * rs[r]);
    }
  }
}

// ---------------- fused GRU, LDS-DMA double-buffered weights ----------------
// out = (1-u)*h + u*tanh([emb | sig(r)*h] @ Wc + bc); u = sig([emb|h]@Wz+bz)
// Weights stream global->LDS once per BLOCK (was: once per WAVE from L2) via
// async global_load_lds; two 16KB ring slots; __syncthreads drains the DMA.
__global__ __launch_bounds__(256, 2) void k_gru(
    const u16* __restrict__ emb, const float* __restrict__ h,
    const u16* __restrict__ Btz, const u16* __restrict__ Btr, const u16* __restrict__ Btc,
    const float* __restrict__ bz, const float* __restrict__ br, const float* __restrict__ bc,
    float* __restrict__ out, int M) {
  __shared__ __align__(16) u16 ring[2][8192];   // 2 x (z 8KB | r 8KB); c-pass uses low 8KB
  __shared__ __align__(16) u16 at[8192];        // 16 KB rh A-tile, stride 128
  int tid = threadIdx.x;
  int lane = tid & 63, wave = tid >> 6;
  int ln = lane & 15, quad = lane >> 4;
  int rowbase = blockIdx.x * 64 + wave * 16;
  int rowA = rowbase + ln;
  long rA = (rowA < M) ? rowA : (M - 1);
  int rb = rowbase + quad * 4;

  // stage zr chunk k (8KB of Bz + 8KB of Br) into slot s: 4 DMA instrs/wave
  auto stage_zr = [&](int k, int s) {
#pragma unroll
    for (int i = 0; i < 2; ++i) {
      int off = (wave * 2 + i) * 512;
      ld_lds16(Btz + k * 4096 + off + lane * 8, &ring[s][off]);
      ld_lds16(Btr + k * 4096 + off + lane * 8, &ring[s][4096 + off]);
    }
  };
  // stage c chunk k (8KB of Bc) into slot s low half: 2 DMA instrs/wave
  auto stage_c = [&](int k, int s) {
#pragma unroll
    for (int i = 0; i < 2; ++i) {
      int off = (wave * 2 + i) * 512;
      ld_lds16(Btc + k * 4096 + off + lane * 8, &ring[s][off]);
    }
  };

  // prologue: slot0 DMA in flight while A-fragments load
  stage_zr(0, 0);

  bf8 af_e[4], af_h[4];
#pragma unroll
  for (int ks = 0; ks < 4; ++ks)
    af_e[ks] = *(const bf8*)(emb + rA * 128 + ks * 32 + quad * 8);
#pragma unroll
  for (int ks = 0; ks < 4; ++ks)
    af_h[ks] = cvt8(h + rA * 128 + ks * 32 + quad * 8);

  f32x4 accz[8], accr[8];
#pragma unroll
  for (int c = 0; c < 8; ++c) {
    accz[c][0] = 0.f; accz[c][1] = 0.f; accz[c][2] = 0.f; accz[c][3] = 0.f;
    accr[c][0] = 0.f; accr[c][1] = 0.f; accr[c][2] = 0.f; accr[c][3] = 0.f;
  }

  __syncthreads();   // slot0 landed (syncthreads drains vmcnt+lgkmcnt)

  // z/r pass: 8 K-chunks, double-buffered
#pragma unroll
  for (int k = 0; k < 8; ++k) {
    if (k < 7) stage_zr(k + 1, (k + 1) & 1);
    bf8 af = (k < 4) ? af_e[k] : af_h[k - 4];
    int s = k & 1;
#pragma unroll
    for (int c = 0; c < 8; ++c) {
      bf8 bz_ = *(const bf8*)(&ring[s][(c * 64 + lane) * 8]);
      bf8 br_ = *(const bf8*)(&ring[s][4096 + (c * 64 + lane) * 8]);
      accz[c] = __builtin_amdgcn_mfma_f32_16x16x32_bf16(af, bz_, accz[c], 0, 0, 0);
      accr[c] = __builtin_amdgcn_mfma_f32_16x16x32_bf16(af, br_, accr[c], 0, 0, 0);
    }
    __syncthreads();  // stage k+1 done; slot s reads finished before its restage at k+1
  }

  // c-chunk 0 DMA hides under the u/rh epilogue
  stage_c(0, 0);

  // h at C-layout positions (for rh and final blend)
  f32x4 hc[8];
#pragma unroll
  for (int c = 0; c < 8; ++c) {
    int col = c * 16 + ln;
#pragma unroll
    for (int r = 0; r < 4; ++r) {
      int row = rb + r;
      hc[c][r] = (row < M) ? h[(size_t)row * 128 + col] : 0.0f;
    }
  }

  // u = sigmoid(accz+bz); rh = sigmoid(accr+br)*h -> at (A-source tile)
#pragma unroll
  for (int c = 0; c < 8; ++c) {
    int col = c * 16 + ln;
    float bzc = bz[col], brc = br[col];
#pragma unroll
    for (int r = 0; r < 4; ++r) {
      float uu = sigf(accz[c][r] + bzc);
      float rr = sigf(accr[c][r] + brc);
      accz[c][r] = uu;                       // keep u in registers
      int lrow = wave * 16 + quad * 4 + r;   // local block row
      at[lrow * 128 + col] = f2b(rr * hc[c][r]);
      accr[c][r] = 0.0f;                     // accr becomes candidate accumulator
    }
  }
  __syncthreads();                           // at visible + c-chunk0 landed

  bf8 af_at[4];
#pragma unroll
  for (int ks = 0; ks < 4; ++ks)
    af_at[ks] = *(const bf8*)(at + (wave * 16 + ln) * 128 + ks * 32 + quad * 8);

  // candidate pass: 8 K-chunks, double-buffered
#pragma unroll
  for (int j = 0; j < 8; ++j) {
    if (j < 7) stage_c(j + 1, (j + 1) & 1);
    bf8 af = (j < 4) ? af_e[j] : af_at[j - 4];
    int s = j & 1;
#pragma unroll
    for (int c = 0; c < 8; ++c) {
      bf8 bfr = *(const bf8*)(&ring[s][(c * 64 + lane) * 8]);
      accr[c] = __builtin_amdgcn_mfma_f32_16x16x32_bf16(af, bfr, accr[c], 0, 0, 0);
    }
    if (j < 7) __syncthreads();
  }

  // epilogue: out = (1-u)*h + u*tanh(accc + bc)
#pragma unroll
  for (int c = 0; c < 8; ++c) {
    int col = c * 16 + ln;
    float bcc = bc[col];
#pragma unroll
    for (int r = 0; r < 4; ++r) {
      int row = rb + r;
      if (row < M) {
        float cd = tanhfast(accr[c][r] + bcc);
        float uu = accz[c][r];
        out[(size_t)row * 128 + col] = (1.0f - uu) * hc[c][r] + uu * cd;
      }
    }
  }
}

extern "C" void kernel_launch(void* const* d_in, const int* in_sizes, int n_in,
                              void* d_out, int out_size, void* d_ws, size_t ws_size,
                              hipStream_t stream) {
  const float* x     = (const float*)d_in[0];
  const float* h     = (const float*)d_in[1];
  const int*   ei    = (const int*)d_in[2];
  const float* W_in  = (const float*)d_in[3];
  const float* b_in  = (const float*)d_in[4];
  const float* W_hid = (const float*)d_in[5];
  const float* b_hid = (const float*)d_in[6];
  const float* W_z   = (const float*)d_in[7];
  const float* b_z   = (const float*)d_in[8];
  const float* W_r   = (const float*)d_in[9];
  const float* b_r   = (const float*)d_in[10];
  const float* W_c   = (const float*)d_in[11];
  const float* b_c   = (const float*)d_in[12];

  const int N = in_sizes[0] / 128;
  const int E = in_sizes[2] / 2;
  const int* src = ei;
  const int* dst = ei + E;

  char* p = (char*)d_ws;
  auto carve = [&](size_t bytes) { char* r = p; p += (bytes + 255) & ~(size_t)255; return r; };
  u16* Bt_in   = (u16*)carve((size_t)16384 * 2);
  u16* Bt_hid  = (u16*)carve((size_t)16384 * 2);
  u16* Bt_z    = (u16*)carve((size_t)32768 * 2);
  u16* Bt_r    = (u16*)carve((size_t)32768 * 2);
  u16* Bt_c    = (u16*)carve((size_t)32768 * 2);
  int* cnt  = (int*)carve((size_t)N * 4);
  int* csr  = (int*)carve((size_t)N * CSR_STRIDE * 4);
  u16* y    = (u16*)carve((size_t)N * 128 * 2);    // bf16 intermediates
  u16* h1   = (u16*)carve((size_t)N * 128 * 2);
  u16* emb  = (u16*)carve((size_t)N * 128 * 2);

  int gN = (N + 255) / 256;
  int gE = (E + 255) / 256;
  int gG = (N + 63) / 64;      // GEMM/GRU: 64 rows per block
  int gA = (N + 3) / 4;        // AGG: 4 waves (nodes) per block

  k_transpose<<<64 + gN, 256, 0, stream>>>(W_in, W_hid, W_z, W_r, W_c,
                                           Bt_in, Bt_hid, Bt_z, Bt_r, Bt_c, cnt, N);
  k_fill<<<gE, 256, 0, stream>>>(src, dst, cnt, csr, E);

  // layer 1: y = (x @ W_in) * dinv ; h1 = relu(dinv * agg(y) + b_in)
  k_gemm<true><<<gG, 256, 0, stream>>>(x, Bt_in, cnt, y, N);
  k_agg<<<gA, 256, 0, stream>>>(y, cnt, csr, b_in, h1, 1, N);
  // layer 2: y = (h1 @ W_hid) * dinv ; emb = dinv * agg(y) + b_hid
  k_gemm<false><<<gG, 256, 0, stream>>>(h1, Bt_hid, cnt, y, N);
  k_agg<<<gA, 256, 0, stream>>>(y, cnt, csr, b_hid, emb, 0, N);
  // fused GRU
  k_gru<<<gG, 256, 0, stream>>>(emb, h, Bt_z, Bt_r, Bt_c, b_z, b_r, b_c, (float*)d_out, N);
}

// Round 3
// 255.521 us; speedup vs baseline: 1.0471x; 1.0287x over previous
//
#include <hip/hip_runtime.h>
#include <cstdint>
#include <cstddef>

typedef unsigned short u16;
typedef unsigned int   u32;

typedef __bf16 bf8   __attribute__((ext_vector_type(8)));
typedef float  f32x4 __attribute__((ext_vector_type(4)));

__device__ __forceinline__ float b2f(u16 v) {
  union { u32 i; float f; } c; c.i = ((u32)v) << 16; return c.f;
}
__device__ __forceinline__ u16 f2b(float f) {
  union { u32 i; float f; } c; c.f = f;
  u32 x = c.i;
  u32 r = (x + 0x7FFFu + ((x >> 16) & 1u)) >> 16;
  return (u16)r;
}
__device__ __forceinline__ float sigf(float x) { return 1.0f / (1.0f + __expf(-x)); }
__device__ __forceinline__ float tanhfast(float x) { return 2.0f * sigf(2.0f * x) - 1.0f; }

// convert 8 consecutive floats to a bf16x8 fragment (RNE)
__device__ __forceinline__ bf8 cvt8(const float* __restrict__ p) {
  f32x4 lo = *(const f32x4*)p;
  f32x4 hi = *(const f32x4*)(p + 4);
  union { u16 s[8]; bf8 v; } c;
#pragma unroll
  for (int i = 0; i < 4; ++i) { c.s[i] = f2b(lo[i]); c.s[4 + i] = f2b(hi[i]); }
  return c.v;
}

// async 16B global -> LDS (dest = wave-uniform base + lane*16)
__device__ __forceinline__ void ld_lds16(const u16* g, u16* l) {
  __builtin_amdgcn_global_load_lds((const __attribute__((address_space(1))) void*)g,
                                   (__attribute__((address_space(3))) void*)l, 16, 0, 0);
}

#define CSR_STRIDE 80

// ---- weight repack: W fp32 [K x 128] -> Bt bf16 in MFMA-fragment order ----
// frag id f = (hh*4+ks)*512 + c*64 + lane ; element j in [0,8):
//   Bt[f*8+j] = bf16( W[(hh*128+ks*32+quad*8+j)*128 + (c*16+ln)] )   (lane=quad*16+ln)
// blocks >= 64 zero the degree-count array instead.
__global__ __launch_bounds__(256) void k_transpose(
    const float* __restrict__ W0, const float* __restrict__ W1,
    const float* __restrict__ W2, const float* __restrict__ W3,
    const float* __restrict__ W4,
    u16* __restrict__ B0, u16* __restrict__ B1, u16* __restrict__ B2,
    u16* __restrict__ B3, u16* __restrict__ B4,
    int* __restrict__ cnt, int N) {
  if (blockIdx.x >= 64) {
    int i = (blockIdx.x - 64) * 256 + threadIdx.x;
    if (i < N) cnt[i] = 0;
    return;
  }
  int t = blockIdx.x * 256 + threadIdx.x;
  const float* in; u16* out; int f;
  if (t < 2048)       { in = W0; out = B0; f = t; }
  else if (t < 4096)  { in = W1; out = B1; f = t - 2048; }
  else if (t < 8192)  { in = W2; out = B2; f = t - 4096; }
  else if (t < 12288) { in = W3; out = B3; f = t - 8192; }
  else                { in = W4; out = B4; f = t - 12288; }
  int ln = f & 15, quad = (f >> 4) & 3, c = (f >> 6) & 7, ks = (f >> 9) & 3, hh = f >> 11;
  int n = c * 16 + ln;
  int k0 = hh * 128 + ks * 32 + quad * 8;
  union { u16 s[8]; uint4 q; } tmp;
#pragma unroll
  for (int j = 0; j < 8; ++j) tmp.s[j] = f2b(in[(size_t)(k0 + j) * 128 + n]);
  *(uint4*)(out + (size_t)f * 8) = tmp.q;
}

// ---------------- CSR build: one pass; cnt doubles as cursor and final degree ----------------
__global__ void k_fill(const int* __restrict__ src, const int* __restrict__ dst,
                       int* __restrict__ cnt, int* __restrict__ csr, int E) {
  int e = blockIdx.x * 256 + threadIdx.x;
  if (e < E) {
    int d = dst[e];
    int pos = atomicAdd(&cnt[d], 1);
    if (pos < CSR_STRIDE) csr[(size_t)d * CSR_STRIDE + pos] = src[e];
  }
}

// ---------------- aggregation: one wave per node, 4 edges x 16-lane x 16B ----------------
// out[d] = postproc( rsqrt(deg+1) * (sum_{s->d} y[s] + y[d]) + bias )
__global__ __launch_bounds__(256) void k_agg(const u16* __restrict__ y,
                                             const int* __restrict__ cnt,
                                             const int* __restrict__ csr,
                                             const float* __restrict__ bias,
                                             u16* __restrict__ out, int relu, int N) {
  int wv = (blockIdx.x * 256 + threadIdx.x) >> 6;
  int lane = threadIdx.x & 63;
  if (wv >= N) return;
  int g = lane >> 4, t = lane & 15;
  const uint4* yq = (const uint4*)y;        // 16 uint4 per 128-feat bf16 row
  int deg = cnt[wv];
  int degc = (deg < 64) ? deg : 64;
  long base = (long)wv * CSR_STRIDE;
  int myidx = (lane < degc) ? csr[base + lane] : 0;

  float a[8];
#pragma unroll
  for (int j = 0; j < 8; ++j) a[j] = 0.0f;

  for (int b = 0; b < degc; b += 8) {
    int e0 = b + g, e1 = b + 4 + g;
    int s0 = __shfl(myidx, (e0 < degc) ? e0 : 0, 64);
    int s1 = __shfl(myidx, (e1 < degc) ? e1 : 0, 64);
    uint4 v0 = yq[(size_t)s0 * 16 + t];
    uint4 v1 = yq[(size_t)s1 * 16 + t];
    if (e0 < degc) {
      const u32* w = (const u32*)&v0;
#pragma unroll
      for (int i = 0; i < 4; ++i) { a[2*i] += b2f((u16)(w[i] & 0xFFFF)); a[2*i+1] += b2f((u16)(w[i] >> 16)); }
    }
    if (e1 < degc) {
      const u32* w = (const u32*)&v1;
#pragma unroll
      for (int i = 0; i < 4; ++i) { a[2*i] += b2f((u16)(w[i] & 0xFFFF)); a[2*i+1] += b2f((u16)(w[i] >> 16)); }
    }
  }
  // cross-group reduction: groups 0..3 hold partial sums of the same feature slice
#pragma unroll
  for (int j = 0; j < 8; ++j) {
    a[j] += __shfl_xor(a[j], 16, 64);
    a[j] += __shfl_xor(a[j], 32, 64);
  }
  if (g == 0) {
    // rare tail deg in (64, 80): add serially (16 lanes do full rows)
    int degt = (deg < CSR_STRIDE) ? deg : CSR_STRIDE;
    for (int p = 64; p < degt; ++p) {
      int s = csr[base + p];
      uint4 v = yq[(size_t)s * 16 + t];
      const u32* w = (const u32*)&v;
#pragma unroll
      for (int i = 0; i < 4; ++i) { a[2*i] += b2f((u16)(w[i] & 0xFFFF)); a[2*i+1] += b2f((u16)(w[i] >> 16)); }
    }
    // self-loop
    uint4 sv = yq[(size_t)wv * 16 + t];
    const u32* w = (const u32*)&sv;
#pragma unroll
    for (int i = 0; i < 4; ++i) { a[2*i] += b2f((u16)(w[i] & 0xFFFF)); a[2*i+1] += b2f((u16)(w[i] >> 16)); }
    float di = rsqrtf((float)deg + 1.0f);
    f32x4 b0 = *(const f32x4*)(bias + t * 8);
    f32x4 b1 = *(const f32x4*)(bias + t * 8 + 4);
    union { u16 s[8]; uint4 q; } o;
#pragma unroll
    for (int j = 0; j < 8; ++j) {
      float r = di * a[j] + ((j < 4) ? b0[j] : b1[j - 4]);
      if (relu) r = fmaxf(r, 0.0f);
      o.s[j] = f2b(r);
    }
    ((uint4*)out)[(size_t)wv * 16 + t] = o.q;
  }
}

// ---------------- layer GEMM: y[M,128] = bf16( (A[M,128] @ W) * rsqrt(deg+1)[row] ) ----------------
template <bool AF>   // A is fp32 (convert) or bf16
__global__ __launch_bounds__(256) void k_gemm(
    const void* __restrict__ Av,
    const u16* __restrict__ Bt,          // fragment-ordered, 16384 u16
    const int* __restrict__ cnt,
    u16* __restrict__ outb, int M) {
  __shared__ __align__(16) u16 bs[16384];
  int tid = threadIdx.x;
  int lane = tid & 63, wave = tid >> 6;
  int ln = lane & 15, quad = lane >> 4;
  int rowbase = blockIdx.x * 64 + wave * 16;
  int rowA = rowbase + ln;
  long rA = (rowA < M) ? rowA : (M - 1);

  {
    const u16* g = Bt + wave * 4096 + lane * 8;
    u16* l = bs + wave * 4096;
#pragma unroll
    for (int i = 0; i < 8; ++i) ld_lds16(g + i * 512, l + i * 512);
  }

  bf8 af[4];
#pragma unroll
  for (int ks = 0; ks < 4; ++ks) {
    int kk = ks * 32 + quad * 8;
    if (AF) af[ks] = cvt8((const float*)Av + rA * 128 + kk);
    else    af[ks] = *(const bf8*)((const u16*)Av + rA * 128 + kk);
  }

  f32x4 acc[8];
#pragma unroll
  for (int c = 0; c < 8; ++c) { acc[c][0] = 0.f; acc[c][1] = 0.f; acc[c][2] = 0.f; acc[c][3] = 0.f; }

  __syncthreads();   // drains the async LDS DMA
#pragma unroll
  for (int ks = 0; ks < 4; ++ks) {
#pragma unroll
    for (int c = 0; c < 8; ++c) {
      bf8 bfr = *(const bf8*)(bs + ks * 4096 + c * 512 + lane * 8);
      acc[c] = __builtin_amdgcn_mfma_f32_16x16x32_bf16(af[ks], bfr, acc[c], 0, 0, 0);
    }
  }

  int rb = rowbase + quad * 4;
  float rs[4];
#pragma unroll
  for (int r = 0; r < 4; ++r) {
    int row = rb + r;
    rs[r] = (row < M) ? rsqrtf((float)cnt[row] + 1.0f) : 0.0f;
  }
#pragma unroll
  for (int c = 0; c < 8; ++c) {
    int col = c * 16 + ln;
#pragma unroll
    for (int r = 0; r < 4; ++r) {
      int row = rb + r;
      if (row < M) outb[(size_t)row * 128 + col] = f2b(acc[c][r] * rs[r]);
    }
  }
}

// ---------------- fused GRU: counted-vmcnt pipeline (T3+T4), 3-slot LDS ring ----------------
// out = (1-u)*h + u*tanh([emb | sig(r)*h] @ Wc + bc); u = sig([emb|h]@Wz+bz)
// Main loops never drain vmcnt to 0: s_waitcnt vmcnt(4|2) + raw s_barrier keeps
// the next chunks' DMA in flight across barriers (depth-2 prefetch).
// LDS map (u16 idx): zr-ring slot s = [s*8192, s*8192+8192) s=0..2 (z low 4096 | r high 4096)
//                    c-ring  slot j = [j*4096, j*4096+4096) j=0..2 (overlays zr slots 0,1lo;
//                      safe: c0/c1 issued after zr-iter7 barrier [slot0 last read iter6];
//                      c2 first issued after the full __syncthreads at the at-handoff)
//                    at = [24576, 32768)  (16 KB rh A-tile, stride 128)
__global__ __launch_bounds__(256, 2) void k_gru(
    const u16* __restrict__ emb, const float* __restrict__ h,
    const u16* __restrict__ Btz, const u16* __restrict__ Btr, const u16* __restrict__ Btc,
    const float* __restrict__ bz, const float* __restrict__ br, const float* __restrict__ bc,
    float* __restrict__ out, int M) {
  __shared__ __align__(16) u16 lds[32768];   // 64 KB total
  u16* const at = lds + 24576;
  int tid = threadIdx.x;
  int lane = tid & 63, wave = tid >> 6;
  int ln = lane & 15, quad = lane >> 4;
  int rowbase = blockIdx.x * 64 + wave * 16;
  int rowA = rowbase + ln;
  long rA = (rowA < M) ? rowA : (M - 1);
  int rb = rowbase + quad * 4;

  // stage zr chunk k into ring slot s: 4 DMA instrs/wave (16 KB/block)
  auto stage_zr = [&](int k, int s) {
#pragma unroll
    for (int i = 0; i < 2; ++i) {
      int off = (wave * 2 + i) * 512;
      ld_lds16(Btz + k * 4096 + off + lane * 8, &lds[s * 8192 + off]);
      ld_lds16(Btr + k * 4096 + off + lane * 8, &lds[s * 8192 + 4096 + off]);
    }
  };
  // stage c chunk k into c-slot s: 2 DMA instrs/wave (8 KB/block)
  auto stage_c = [&](int k, int s) {
#pragma unroll
    for (int i = 0; i < 2; ++i) {
      int off = (wave * 2 + i) * 512;
      ld_lds16(Btc + k * 4096 + off + lane * 8, &lds[s * 4096 + off]);
    }
  };

  // prologue: depth-2 prefetch in flight while A-fragments load
  stage_zr(0, 0);
  stage_zr(1, 1);

  bf8 af_e[4], af_h[4];
#pragma unroll
  for (int ks = 0; ks < 4; ++ks)
    af_e[ks] = *(const bf8*)(emb + rA * 128 + ks * 32 + quad * 8);
#pragma unroll
  for (int ks = 0; ks < 4; ++ks)
    af_h[ks] = cvt8(h + rA * 128 + ks * 32 + quad * 8);

  f32x4 accz[8], accr[8];
#pragma unroll
  for (int c = 0; c < 8; ++c) {
    accz[c][0] = 0.f; accz[c][1] = 0.f; accz[c][2] = 0.f; accz[c][3] = 0.f;
    accr[c][0] = 0.f; accr[c][1] = 0.f; accr[c][2] = 0.f; accr[c][3] = 0.f;
  }

  // z/r pass: 8 K-chunks. Per iter: wait chunk k landed (vmcnt leaves the
  // newest 4 DMAs = chunk k+1 outstanding), barrier, stage k+2, compute k.
#pragma unroll
  for (int k = 0; k < 8; ++k) {
    if (k < 7) asm volatile("s_waitcnt vmcnt(4)\n\ts_barrier" ::: "memory");
    else       asm volatile("s_waitcnt vmcnt(0)\n\ts_barrier" ::: "memory");
    if (k < 6) stage_zr(k + 2, (k + 2) % 3);
    bf8 af = (k < 4) ? af_e[k] : af_h[k - 4];
    int s = k % 3;
#pragma unroll
    for (int c = 0; c < 8; ++c) {
      bf8 bz_ = *(const bf8*)(&lds[s * 8192 + (c * 64 + lane) * 8]);
      bf8 br_ = *(const bf8*)(&lds[s * 8192 + 4096 + (c * 64 + lane) * 8]);
      accz[c] = __builtin_amdgcn_mfma_f32_16x16x32_bf16(af, bz_, accz[c], 0, 0, 0);
      accr[c] = __builtin_amdgcn_mfma_f32_16x16x32_bf16(af, br_, accr[c], 0, 0, 0);
    }
  }

  // c chunks 0,1 DMA hide under the u/rh epilogue (drained by the syncthreads below)
  stage_c(0, 0);
  stage_c(1, 1);

  // h at C-layout positions (for rh and final blend)
  f32x4 hc[8];
#pragma unroll
  for (int c = 0; c < 8; ++c) {
    int col = c * 16 + ln;
#pragma unroll
    for (int r = 0; r < 4; ++r) {
      int row = rb + r;
      hc[c][r] = (row < M) ? h[(size_t)row * 128 + col] : 0.0f;
    }
  }

  // u = sigmoid(accz+bz); rh = sigmoid(accr+br)*h -> at (A-source tile)
#pragma unroll
  for (int c = 0; c < 8; ++c) {
    int col = c * 16 + ln;
    float bzc = bz[col], brc = br[col];
#pragma unroll
    for (int r = 0; r < 4; ++r) {
      float uu = sigf(accz[c][r] + bzc);
      float rr = sigf(accr[c][r] + brc);
      accz[c][r] = uu;                       // keep u in registers
      int lrow = wave * 16 + quad * 4 + r;   // local block row
      at[lrow * 128 + col] = f2b(rr * hc[c][r]);
      accr[c][r] = 0.0f;                     // accr becomes candidate accumulator
    }
  }
  __syncthreads();   // full drain: at visible, c chunks 0,1 landed, zr reads all done

  bf8 af_at[4];
#pragma unroll
  for (int ks = 0; ks < 4; ++ks)
    af_at[ks] = *(const bf8*)(at + (wave * 16 + ln) * 128 + ks * 32 + quad * 8);

  // candidate pass: 8 K-chunks, same counted-vmcnt structure (2 DMAs/stage)
#pragma unroll
  for (int j = 0; j < 8; ++j) {
    if (j < 7) asm volatile("s_waitcnt vmcnt(2)\n\ts_barrier" ::: "memory");
    else       asm volatile("s_waitcnt vmcnt(0)\n\ts_barrier" ::: "memory");
    if (j < 6) stage_c(j + 2, (j + 2) % 3);
    bf8 af = (j < 4) ? af_e[j] : af_at[j - 4];
    int s = j % 3;
#pragma unroll
    for (int c = 0; c < 8; ++c) {
      bf8 bfr = *(const bf8*)(&lds[s * 4096 + (c * 64 + lane) * 8]);
      accr[c] = __builtin_amdgcn_mfma_f32_16x16x32_bf16(af, bfr, accr[c], 0, 0, 0);
    }
  }

  // epilogue: out = (1-u)*h + u*tanh(accc + bc)
#pragma unroll
  for (int c = 0; c < 8; ++c) {
    int col = c * 16 + ln;
    float bcc = bc[col];
#pragma unroll
    for (int r = 0; r < 4; ++r) {
      int row = rb + r;
      if (row < M) {
        float cd = tanhfast(accr[c][r] + bcc);
        float uu = accz[c][r];
        out[(size_t)row * 128 + col] = (1.0f - uu) * hc[c][r] + uu * cd;
      }
    }
  }
}

extern "C" void kernel_launch(void* const* d_in, const int* in_sizes, int n_in,
                              void* d_out, int out_size, void* d_ws, size_t ws_size,
                              hipStream_t stream) {
  const float* x     = (const float*)d_in[0];
  const float* h     = (const float*)d_in[1];
  const int*   ei    = (const int*)d_in[2];
  const float* W_in  = (const float*)d_in[3];
  const float* b_in  = (const float*)d_in[4];
  const float* W_hid = (const float*)d_in[5];
  const float* b_hid = (const float*)d_in[6];
  const float* W_z   = (const float*)d_in[7];
  const float* b_z   = (const float*)d_in[8];
  const float* W_r   = (const float*)d_in[9];
  const float* b_r   = (const float*)d_in[10];
  const float* W_c   = (const float*)d_in[11];
  const float* b_c   = (const float*)d_in[12];

  const int N = in_sizes[0] / 128;
  const int E = in_sizes[2] / 2;
  const int* src = ei;
  const int* dst = ei + E;

  char* p = (char*)d_ws;
  auto carve = [&](size_t bytes) { char* r = p; p += (bytes + 255) & ~(size_t)255; return r; };
  u16* Bt_in   = (u16*)carve((size_t)16384 * 2);
  u16* Bt_hid  = (u16*)carve((size_t)16384 * 2);
  u16* Bt_z    = (u16*)carve((size_t)32768 * 2);
  u16* Bt_r    = (u16*)carve((size_t)32768 * 2);
  u16* Bt_c    = (u16*)carve((size_t)32768 * 2);
  int* cnt  = (int*)carve((size_t)N * 4);
  int* csr  = (int*)carve((size_t)N * CSR_STRIDE * 4);
  u16* y    = (u16*)carve((size_t)N * 128 * 2);    // bf16 intermediates
  u16* h1   = (u16*)carve((size_t)N * 128 * 2);
  u16* emb  = (u16*)carve((size_t)N * 128 * 2);

  int gN = (N + 255) / 256;
  int gE = (E + 255) / 256;
  int gG = (N + 63) / 64;      // GEMM/GRU: 64 rows per block
  int gA = (N + 3) / 4;        // AGG: 4 waves (nodes) per block

  k_transpose<<<64 + gN, 256, 0, stream>>>(W_in, W_hid, W_z, W_r, W_c,
                                           Bt_in, Bt_hid, Bt_z, Bt_r, Bt_c, cnt, N);
  k_fill<<<gE, 256, 0, stream>>>(src, dst, cnt, csr, E);

  // layer 1: y = (x @ W_in) * dinv ; h1 = relu(dinv * agg(y) + b_in)
  k_gemm<true><<<gG, 256, 0, stream>>>(x, Bt_in, cnt, y, N);
  k_agg<<<gA, 256, 0, stream>>>(y, cnt, csr, b_in, h1, 1, N);
  // layer 2: y = (h1 @ W_hid) * dinv ; emb = dinv * agg(y) + b_hid
  k_gemm<false><<<gG, 256, 0, stream>>>(h1, Bt_hid, cnt, y, N);
  k_agg<<<gA, 256, 0, stream>>>(y, cnt, csr, b_hid, emb, 0, N);
  // fused GRU
  k_gru<<<gG, 256, 0, stream>>>(emb, h, Bt_z, Bt_r, Bt_c, b_z, b_r, b_c, (float*)d_out, N);
}